// Round 1
// baseline (145.314 us; speedup 1.0000x reference)
//
#include <hip/hip_runtime.h>

#define NEMB 64   // K = NUM_BINS + 1
#define DIM  64   // EMB_DIM
#define NBINS 63

// T[i][d] = sum_k weight[k][d] / (|i-k|+1)
__global__ __launch_bounds__(64) void build_table_kernel(
    const float* __restrict__ weight, float* __restrict__ T) {
    const int i = blockIdx.x;    // 0..63 table row
    const int d = threadIdx.x;   // 0..63 embedding dim
    float acc = 0.0f;
    #pragma unroll
    for (int k = 0; k < NEMB; ++k) {
        int diff = i - k;
        diff = diff < 0 ? -diff : diff;
        acc += weight[k * DIM + d] * (1.0f / (float)(diff + 1));
    }
    T[i * DIM + d] = acc;
}

// Each block handles 256 (b,f) rows. Phase 1: per-thread bucketize via
// binary search on the EXACT bin edges (low[1..63]) staged in LDS.
// Phase 2: 16-lane groups stream T[idx] rows out as float4 (coalesced).
__global__ __launch_bounds__(256) void emb_gather_kernel(
    const float* __restrict__ x,
    const float* __restrict__ low,
    const float* __restrict__ T,
    float* __restrict__ out,
    int n_rows) {
    __shared__ float4 Tlds[NEMB * 16];   // 16 KB: T as float4 [64][16]
    __shared__ float  bins_lds[NBINS];   // bins[j] = low[j+1]
    __shared__ int    idx_lds[256];

    const int t = threadIdx.x;

    // Stage table: 1024 float4 loads across 256 threads (coalesced).
    const float4* T4 = reinterpret_cast<const float4*>(T);
    #pragma unroll
    for (int i = 0; i < 4; ++i)
        Tlds[t + 256 * i] = T4[t + 256 * i];
    if (t < NBINS) bins_lds[t] = low[t + 1];
    __syncthreads();

    const int base = blockIdx.x * 256;

    // Phase 1: index = #{ j : x > bins[j] }, computed with exact compares.
    {
        const int row = base + t;
        float xv = (row < n_rows) ? x[row] : 0.0f;
        int c = 0;
        // Branchless binary search; strides 32+16+8+4+2+1 = 63 cover c in [0,63].
        // All probe indices provably stay within [0,62] -> no bounds checks.
        if (xv > bins_lds[c + 31]) c += 32;
        if (xv > bins_lds[c + 15]) c += 16;
        if (xv > bins_lds[c + 7])  c += 8;
        if (xv > bins_lds[c + 3])  c += 4;
        if (xv > bins_lds[c + 1])  c += 2;
        if (xv > bins_lds[c])      c += 1;
        idx_lds[t] = c;
    }
    __syncthreads();

    // Phase 2: group g (16 lanes) writes row (it*16 + g); block writes a
    // contiguous 4 KB segment per iteration.
    const int sub   = t >> 4;   // 0..15 row-group within iteration
    const int lane4 = t & 15;   // float4 slot within the 64-float row
    float4* out4 = reinterpret_cast<float4*>(out);
    #pragma unroll
    for (int it = 0; it < 16; ++it) {
        const int r    = it * 16 + sub;     // row within block
        const int grow = base + r;          // global row
        if (grow < n_rows) {
            const float4 v = Tlds[idx_lds[r] * 16 + lane4];
            out4[grow * 16 + lane4] = v;
        }
    }
}

extern "C" void kernel_launch(void* const* d_in, const int* in_sizes, int n_in,
                              void* d_out, int out_size, void* d_ws, size_t ws_size,
                              hipStream_t stream) {
    const float* x      = (const float*)d_in[0];   // [B*F]
    const float* low    = (const float*)d_in[1];   // [64]  (-inf, bins...)
    const float* weight = (const float*)d_in[3];   // [64*64]
    float* out = (float*)d_out;
    float* T   = (float*)d_ws;                     // 16 KB table scratch

    const int n_rows = in_sizes[0];                // B*F = 524288

    build_table_kernel<<<NEMB, DIM, 0, stream>>>(weight, T);

    const int blocks = (n_rows + 255) / 256;       // 2048
    emb_gather_kernel<<<blocks, 256, 0, stream>>>(x, low, T, out, n_rows);
}